// Round 1
// baseline (3042.024 us; speedup 1.0000x reference)
//
#include <hip/hip_runtime.h>
#include <math.h>

#define NB 4096
#define NR 49
#define NS 50
#define ND 512
#define NK 100

#define CB_STRIDE 260          // chunk buffer row stride in floats (pad to break bank patterns, mult of 4 for b128)
#define NTILE0 (NR * 25)       // 1225 (r, k-quad) tiles for pass 0
#define NTILE1 (NS * 25)       // 1250 tiles for pass 1

struct SharedMem {
    float cbuf[NS * CB_STRIDE];  // 13000 floats = 52 KB: feature d-chunk (50 rows x 256 cols + pad)
    float part[1280];            // per-tile score partials
    float tf_mean[ND];           // mean text feature
    float vi[ND];                // attended image feature
    float tscr[256];             // scratch for vector-matrix dots
    float scores[64];
    float P[64];                 // softmax probabilities
    float consts[2];             // const0 / const1 (text/image conditioning score terms)
};

__global__ __launch_bounds__(256, 2) void coattn_kernel(
    const float* __restrict__ ifeat, const float* __restrict__ tfeat,
    const float* __restrict__ wVi0, const float* __restrict__ wVt0,
    const float* __restrict__ wPi0, const float* __restrict__ bPi0,
    const float* __restrict__ wVi1, const float* __restrict__ wVt1,
    const float* __restrict__ wPi1, const float* __restrict__ bPi1,
    float* __restrict__ out)
{
    __shared__ SharedMem sm;
    const int b = blockIdx.x;
    const int tid = threadIdx.x;
    const float* ig = ifeat + (size_t)b * NR * ND;
    const float* tg = tfeat + (size_t)b * NS * ND;

    // ---------------- Phase A: tfeature = mean_s tfeature_h[b,s,:] ----------------
    {
        const int d0 = tid * 2;
        float ax = 0.f, ay = 0.f;
        for (int s = 0; s < NS; ++s) {
            const float2 v = *reinterpret_cast<const float2*>(tg + s * ND + d0);
            ax += v.x; ay += v.y;
        }
        sm.tf_mean[d0]     = ax * (1.0f / NS);
        sm.tf_mean[d0 + 1] = ay * (1.0f / NS);
    }
    __syncthreads();

    // ---------------- Phase C: wVt0[k] = tf_mean . wVt0[:,k]; const0 ----------------
    {
        const int k = tid & 127, half = tid >> 7;
        float acc = 0.f;
        if (k < NK) {
            const float* wp = wVt0 + half * 256 * NK + k;
            const float* tm = sm.tf_mean + half * 256;
            for (int d = 0; d < 256; ++d) acc += tm[d] * wp[d * NK];
        }
        sm.tscr[tid] = acc;
    }
    __syncthreads();
    if (tid < NK) {
        const float v = sm.tscr[tid] + sm.tscr[128 + tid];
        sm.tscr[tid] = tanhf(v) * wPi0[NK + tid];   // text part of pass-0 score
    }
    __syncthreads();
    if (tid < 64) {
        float v = (tid < NK ? sm.tscr[tid] : 0.f) + (tid + 64 < NK ? sm.tscr[tid + 64] : 0.f);
        for (int off = 32; off; off >>= 1) v += __shfl_xor(v, off);
        if (tid == 0) sm.consts[0] = v;
    }

    // ---------------- Phase D: scores_i via tiled GEMM [49x512]x[512x100] ----------------
    float acc0[5][4];
    int r_[5], koff_[5];
#pragma unroll
    for (int it = 0; it < 5; ++it) {
        const int idx = tid + 256 * it;
        const int idc = (idx < NTILE0) ? idx : 0;
        r_[it] = idc / 25;
        koff_[it] = (idc % 25) * 4;
#pragma unroll
        for (int j = 0; j < 4; ++j) acc0[it][j] = 0.f;
    }
    for (int chunk = 0; chunk < 2; ++chunk) {
        __syncthreads();
        for (int i4 = tid; i4 < NR * 64; i4 += 256) {   // stage ifeature chunk (float4)
            const int row = i4 >> 6, c4 = i4 & 63;
            const float4 v = *reinterpret_cast<const float4*>(ig + row * ND + chunk * 256 + c4 * 4);
            *reinterpret_cast<float4*>(&sm.cbuf[row * CB_STRIDE + c4 * 4]) = v;
        }
        __syncthreads();
        const float* wbase = wVi0 + chunk * 256 * NK;
        for (int d4 = 0; d4 < 64; ++d4) {
            const float* wrow = wbase + d4 * 4 * NK;
#pragma unroll
            for (int it = 0; it < 5; ++it) {
                const float4 a = *reinterpret_cast<const float4*>(&sm.cbuf[r_[it] * CB_STRIDE + d4 * 4]);
                const int ko = koff_[it];
#define STEP0(AV, DD) { const float4 w = *reinterpret_cast<const float4*>(wrow + (DD) * NK + ko); \
                        acc0[it][0] += (AV) * w.x; acc0[it][1] += (AV) * w.y; \
                        acc0[it][2] += (AV) * w.z; acc0[it][3] += (AV) * w.w; }
                STEP0(a.x, 0) STEP0(a.y, 1) STEP0(a.z, 2) STEP0(a.w, 3)
#undef STEP0
            }
        }
    }
#pragma unroll
    for (int it = 0; it < 5; ++it) {
        const int idx = tid + 256 * it;
        if (idx < NTILE0) {
            float local = 0.f;
#pragma unroll
            for (int j = 0; j < 4; ++j) local += tanhf(acc0[it][j]) * wPi0[koff_[it] + j];
            sm.part[idx] = local;
        }
    }
    __syncthreads();
    if (tid < NR) {
        float s = bPi0[tid] + sm.consts[0];
        for (int q = 0; q < 25; ++q) s += sm.part[tid * 25 + q];
        sm.scores[tid] = s;
    }
    __syncthreads();
    if (tid < 64) {   // softmax over R=49
        const float v = (tid < NR) ? sm.scores[tid] : -3.0e38f;
        float m = v;
        for (int off = 32; off; off >>= 1) m = fmaxf(m, __shfl_xor(m, off));
        const float e = (tid < NR) ? __expf(v - m) : 0.f;
        float ssum = e;
        for (int off = 32; off; off >>= 1) ssum += __shfl_xor(ssum, off);
        sm.P[tid] = e / ssum;
    }
    __syncthreads();

    // ---------------- Phase F: Vi = sum_r P[r] * ifeature[b,r,:] ----------------
    {
        const int d0 = tid * 2;
        float ax = 0.f, ay = 0.f;
        for (int r = 0; r < NR; ++r) {
            const float p = sm.P[r];
            const float2 v = *reinterpret_cast<const float2*>(ig + r * ND + d0);
            ax += p * v.x; ay += p * v.y;
        }
        sm.vi[d0] = ax; sm.vi[d0 + 1] = ay;
    }
    __syncthreads();

    // ---------------- Phase G: wVi1[k] = Vi . wVi1[:,k]; const1 ----------------
    {
        const int k = tid & 127, half = tid >> 7;
        float acc = 0.f;
        if (k < NK) {
            const float* wp = wVi1 + half * 256 * NK + k;
            const float* vm = sm.vi + half * 256;
            for (int d = 0; d < 256; ++d) acc += vm[d] * wp[d * NK];
        }
        sm.tscr[tid] = acc;
    }
    __syncthreads();
    if (tid < NK) {
        const float v = sm.tscr[tid] + sm.tscr[128 + tid];
        sm.tscr[tid] = tanhf(v) * wPi1[tid];   // image part of pass-1 score
    }
    __syncthreads();
    if (tid < 64) {
        float v = (tid < NK ? sm.tscr[tid] : 0.f) + (tid + 64 < NK ? sm.tscr[tid + 64] : 0.f);
        for (int off = 32; off; off >>= 1) v += __shfl_xor(v, off);
        if (tid == 0) sm.consts[1] = v;
    }

    // ---------------- Phase H: scores_t via tiled GEMM [50x512]x[512x100] ----------------
    float acc1[5][4];
    int s_[5], k1_[5];
#pragma unroll
    for (int it = 0; it < 5; ++it) {
        const int idx = tid + 256 * it;
        const int idc = (idx < NTILE1) ? idx : 0;
        s_[it] = idc / 25;
        k1_[it] = (idc % 25) * 4;
#pragma unroll
        for (int j = 0; j < 4; ++j) acc1[it][j] = 0.f;
    }
    for (int chunk = 0; chunk < 2; ++chunk) {
        __syncthreads();
        for (int i4 = tid; i4 < NS * 64; i4 += 256) {   // stage tfeature chunk
            const int row = i4 >> 6, c4 = i4 & 63;
            const float4 v = *reinterpret_cast<const float4*>(tg + row * ND + chunk * 256 + c4 * 4);
            *reinterpret_cast<float4*>(&sm.cbuf[row * CB_STRIDE + c4 * 4]) = v;
        }
        __syncthreads();
        const float* wbase = wVt1 + chunk * 256 * NK;
        for (int d4 = 0; d4 < 64; ++d4) {
            const float* wrow = wbase + d4 * 4 * NK;
#pragma unroll
            for (int it = 0; it < 5; ++it) {
                const float4 a = *reinterpret_cast<const float4*>(&sm.cbuf[s_[it] * CB_STRIDE + d4 * 4]);
                const int ko = k1_[it];
#define STEP1(AV, DD) { const float4 w = *reinterpret_cast<const float4*>(wrow + (DD) * NK + ko); \
                        acc1[it][0] += (AV) * w.x; acc1[it][1] += (AV) * w.y; \
                        acc1[it][2] += (AV) * w.z; acc1[it][3] += (AV) * w.w; }
                STEP1(a.x, 0) STEP1(a.y, 1) STEP1(a.z, 2) STEP1(a.w, 3)
#undef STEP1
            }
        }
    }
#pragma unroll
    for (int it = 0; it < 5; ++it) {
        const int idx = tid + 256 * it;
        if (idx < NTILE1) {
            float local = 0.f;
#pragma unroll
            for (int j = 0; j < 4; ++j) local += tanhf(acc1[it][j]) * wPi1[NK + k1_[it] + j];
            sm.part[idx] = local;
        }
    }
    __syncthreads();
    if (tid < NS) {
        float s = bPi1[tid] + sm.consts[1];
        for (int q = 0; q < 25; ++q) s += sm.part[tid * 25 + q];
        sm.scores[tid] = s;
    }
    __syncthreads();
    if (tid < 64) {   // softmax over S=50
        const float v = (tid < NS) ? sm.scores[tid] : -3.0e38f;
        float m = v;
        for (int off = 32; off; off >>= 1) m = fmaxf(m, __shfl_xor(m, off));
        const float e = (tid < NS) ? __expf(v - m) : 0.f;
        float ssum = e;
        for (int off = 32; off; off >>= 1) ssum += __shfl_xor(ssum, off);
        sm.P[tid] = e / ssum;
    }
    __syncthreads();

    // ---------------- Phase J: Vt + Vi -> out ----------------
    {
        const int d0 = tid * 2;
        float ax = 0.f, ay = 0.f;
        for (int s = 0; s < NS; ++s) {
            const float p = sm.P[s];
            const float2 v = *reinterpret_cast<const float2*>(tg + s * ND + d0);
            ax += p * v.x; ay += p * v.y;
        }
        float2 o;
        o.x = sm.vi[d0] + ax;
        o.y = sm.vi[d0 + 1] + ay;
        *reinterpret_cast<float2*>(out + (size_t)b * ND + d0) = o;
    }
}

extern "C" void kernel_launch(void* const* d_in, const int* in_sizes, int n_in,
                              void* d_out, int out_size, void* d_ws, size_t ws_size,
                              hipStream_t stream) {
    const float* ifeat = (const float*)d_in[0];
    const float* tfeat = (const float*)d_in[1];
    const float* wVi0  = (const float*)d_in[2];
    const float* wVt0  = (const float*)d_in[3];
    const float* wPi0  = (const float*)d_in[4];
    const float* bPi0  = (const float*)d_in[5];
    const float* wVi1  = (const float*)d_in[6];
    const float* wVt1  = (const float*)d_in[7];
    const float* wPi1  = (const float*)d_in[8];
    const float* bPi1  = (const float*)d_in[9];
    float* outp = (float*)d_out;

    hipLaunchKernelGGL(coattn_kernel, dim3(NB), dim3(256), 0, stream,
                       ifeat, tfeat, wVi0, wVt0, wPi0, bPi0,
                       wVi1, wVt1, wPi1, bPi1, outp);
}

// Round 2
// 648.548 us; speedup vs baseline: 4.6905x; 4.6905x over previous
//
#include <hip/hip_runtime.h>
#include <math.h>

#define NB 4096
#define NR 49
#define NS 50
#define ND 512
#define NK 100
#define NT 7           // N-tiles of 16 cols (112 >= 100)
#define KSTEPS 16      // 512 / 32
#define FRAGS (NT * KSTEPS * 64 * 8)   // 57344 ushorts (114688 B) per weight matrix

typedef __attribute__((ext_vector_type(8))) short short8;
typedef __attribute__((ext_vector_type(4))) float f32x4;

__device__ __forceinline__ unsigned short f32_bf16(float f) {
    union { float f; unsigned u; } x; x.f = f;
    return (unsigned short)((x.u + 0x7fffu + ((x.u >> 16) & 1u)) >> 16);  // RNE
}
__device__ __forceinline__ float bf16_f32(unsigned short h) {
    union { unsigned u; float f; } x; x.u = ((unsigned)h) << 16;
    return x.f;
}

// ---------------------------------------------------------------------------
// Pre-pass: convert weight matrices [512][100] f32 -> bf16 fragments in MFMA
// B-operand order: frag(t, ks): lane l holds W[k = ks*32 + (l>>4)*8 + j][col = t*16 + (l&15)],
// j = 0..7 contiguous. One coalesced 16B load per fragment in the main kernel.
// ---------------------------------------------------------------------------
__global__ void preswz_kernel(const float* __restrict__ w0, const float* __restrict__ w1,
                              const float* __restrict__ w2, const float* __restrict__ w3,
                              unsigned short* __restrict__ ws)
{
    const int l  = threadIdx.x;          // 64
    const int ks = blockIdx.x & 15;
    const int t  = blockIdx.x >> 4;      // 0..6
    const int m  = blockIdx.y;           // 0..3
    const float* W = (m == 0) ? w0 : (m == 1) ? w1 : (m == 2) ? w2 : w3;
    const int col = t * 16 + (l & 15);
    const int k0  = ks * 32 + (l >> 4) * 8;
    unsigned short* o = ws + (size_t)m * FRAGS + ((size_t)(t * 16 + ks) * 64 + l) * 8;
#pragma unroll
    for (int j = 0; j < 8; ++j) {
        float v = (col < NK) ? W[(size_t)(k0 + j) * NK + col] : 0.f;
        o[j] = f32_bf16(v);
    }
}

// ---------------------------------------------------------------------------
// Main kernel: one block per batch, 512 threads (8 waves).
// ---------------------------------------------------------------------------
struct SM {
    short I[64 * 512];    // ifeature bf16, rows 49..63 zero; 16B-chunk XOR swizzle
    short T[64 * 512];    // tfeature bf16, rows 50..63 zero
    float tf_mean[ND];
    float vi[ND];
    float red[ND];        // cross-half reduction buffer
    float scores[64];     // row partials (n-half 0, incl. bias)
    float part2[64];      // row partials (n-half 1)
    float P[64];
    float scr[8];         // per-wave const-GEMV partials
};

__device__ __forceinline__ void stage_tile(short* __restrict__ dst, const float* __restrict__ src,
                                           int nrows, int tid)
{
    for (int ci = tid; ci < 64 * 64; ci += 512) {
        const int row = ci >> 6, c = ci & 63;
        const int lidx = (row << 9) + ((c ^ (row & 7)) << 3);
        short8 v;
        if (row < nrows) {
            const float* p = src + (row << 9) + (c << 3);
            const float4 a = *reinterpret_cast<const float4*>(p);
            const float4 bq = *reinterpret_cast<const float4*>(p + 4);
            v[0] = (short)f32_bf16(a.x);  v[1] = (short)f32_bf16(a.y);
            v[2] = (short)f32_bf16(a.z);  v[3] = (short)f32_bf16(a.w);
            v[4] = (short)f32_bf16(bq.x); v[5] = (short)f32_bf16(bq.y);
            v[6] = (short)f32_bf16(bq.z); v[7] = (short)f32_bf16(bq.w);
        } else {
            v = short8{0, 0, 0, 0, 0, 0, 0, 0};
        }
        *reinterpret_cast<short8*>(&dst[lidx]) = v;
    }
}

// One score pass: rows-GEMM (A[64x512] x Wrow[512x112]) + const-GEMV (convec x Wconst).
// Wave (m = wid&3) owns rows 16m..16m+15; n-half (wid>>2) owns tiles t0..t0+tcnt-1.
__device__ __forceinline__ void score_pass(
    const short* __restrict__ At, const unsigned short* __restrict__ wsR,
    const unsigned short* __restrict__ wsC, const float* __restrict__ convec,
    const float* __restrict__ wPiRow, const float* __restrict__ wPiConst,
    const float* __restrict__ bvec, int nrows,
    float* __restrict__ outA, float* __restrict__ outB, float* __restrict__ scrw, int tid)
{
    const int lane = tid & 63, wid = tid >> 6;
    const int m = wid & 3, nh = wid >> 2;
    const int t0 = nh * 4, tcnt = nh ? 3 : 4;
    const int colg = lane & 15, g = lane >> 4;
    const int arow = m * 16 + colg;          // A-operand row keyed by lane&15
    const int rswz = arow & 7;

    const unsigned short* wbase[4];
#pragma unroll
    for (int q = 0; q < 4; ++q)
        wbase[q] = wsR + (size_t)(t0 + q) * (KSTEPS * 512) + lane * 8;

    const f32x4 zero4 = {0.f, 0.f, 0.f, 0.f};
    f32x4 acc[4] = {zero4, zero4, zero4, zero4};

    short8 wf[4];
#pragma unroll
    for (int q = 0; q < 4; ++q)
        if (q < tcnt) wf[q] = *reinterpret_cast<const short8*>(wbase[q]);

    for (int ks = 0; ks < KSTEPS; ++ks) {
        const short8 a = *reinterpret_cast<const short8*>(
            &At[arow * 512 + (((ks * 4 + g) ^ rswz) << 3)]);
        short8 wn[4];
        if (ks + 1 < KSTEPS) {
#pragma unroll
            for (int q = 0; q < 4; ++q)
                if (q < tcnt) wn[q] = *reinterpret_cast<const short8*>(wbase[q] + (ks + 1) * 512);
        } else {
#pragma unroll
            for (int q = 0; q < 4; ++q) wn[q] = wf[q];
        }
#pragma unroll
        for (int q = 0; q < 4; ++q)
            if (q < tcnt) acc[q] = __builtin_amdgcn_mfma_f32_16x16x32_bf16(a, wf[q], acc[q], 0, 0, 0);
#pragma unroll
        for (int q = 0; q < 4; ++q) wf[q] = wn[q];
    }

    // rows epilogue: s[row] = sum_cols tanh(D) * wPiRow; shfl-reduce cols (16 lanes)
    float s[4] = {0.f, 0.f, 0.f, 0.f};
#pragma unroll
    for (int q = 0; q < 4; ++q)
        if (q < tcnt) {
            const int col = (t0 + q) * 16 + colg;
            const float w = (col < NK) ? wPiRow[col] : 0.f;
#pragma unroll
            for (int i = 0; i < 4; ++i) s[i] += tanhf(acc[q][i]) * w;
        }
#pragma unroll
    for (int off = 1; off < 16; off <<= 1) {
#pragma unroll
        for (int i = 0; i < 4; ++i) s[i] += __shfl_xor(s[i], off);
    }
    if (colg == 0) {
        float* o = nh ? outB : outA;
        const int rbase = m * 16 + g * 4;
#pragma unroll
        for (int i = 0; i < 4; ++i) {
            const int r = rbase + i;
            if (r < nrows) o[r] = s[i] + (nh ? 0.f : bvec[r]);
        }
    }

    // const GEMV: wave wid (<7) computes row-0-only MFMA tile of convec x Wconst
    f32x4 accC = zero4;
    if (wid < NT) {
        const unsigned short* wc = wsC + (size_t)wid * (KSTEPS * 512) + lane * 8;
        for (int ks = 0; ks < KSTEPS; ++ks) {
            short8 a = {0, 0, 0, 0, 0, 0, 0, 0};
            if (colg == 0) {
                const float* cp = convec + ks * 32 + g * 8;
#pragma unroll
                for (int j = 0; j < 8; ++j) a[j] = (short)f32_bf16(cp[j]);
            }
            const short8 w = *reinterpret_cast<const short8*>(wc + ks * 512);
            accC = __builtin_amdgcn_mfma_f32_16x16x32_bf16(a, w, accC, 0, 0, 0);
        }
    }
    float cpv = 0.f;
    if (wid < NT && lane < 16) {
        const int col = wid * 16 + colg;
        if (col < NK) cpv = tanhf(accC[0]) * wPiConst[col];
    }
#pragma unroll
    for (int off = 1; off < 16; off <<= 1) cpv += __shfl_xor(cpv, off);
    if (lane == 0) scrw[wid] = cpv;
}

__global__ __launch_bounds__(512, 1) void coattn_main(
    const float* __restrict__ ifeat, const float* __restrict__ tfeat,
    const float* __restrict__ wPi0, const float* __restrict__ bPi0,
    const float* __restrict__ wPi1, const float* __restrict__ bPi1,
    const unsigned short* __restrict__ wsW, float* __restrict__ out)
{
    __shared__ SM sm;
    const int b = blockIdx.x, tid = threadIdx.x;
    const float* ig = ifeat + (size_t)b * NR * ND;
    const float* tg = tfeat + (size_t)b * NS * ND;

    stage_tile(sm.I, ig, NR, tid);
    stage_tile(sm.T, tg, NS, tid);
    __syncthreads();

    const int dh = tid & 255, half = tid >> 8, d0 = dh * 2;

    // ---- phase A: tf_mean = mean_s T[s,:] (split rows across halves)
    {
        float ax = 0.f, ay = 0.f;
        const int r0 = half * 25;
        for (int r = r0; r < r0 + 25; ++r) {
            const unsigned u = *reinterpret_cast<const unsigned*>(
                &sm.T[r * 512 + (((d0 >> 3) ^ (r & 7)) << 3) + (d0 & 7)]);
            ax += bf16_f32((unsigned short)(u & 0xffffu));
            ay += bf16_f32((unsigned short)(u >> 16));
        }
        if (half) { sm.red[d0] = ax; sm.red[d0 + 1] = ay; }
        __syncthreads();
        if (!half) {
            sm.tf_mean[d0]     = (ax + sm.red[d0]) * (1.f / NS);
            sm.tf_mean[d0 + 1] = (ay + sm.red[d0 + 1]) * (1.f / NS);
        }
    }
    __syncthreads();

    // ---- pass 0: scores_i = tanh(I x Wvi0)*wPi0[:100] + tanh(tf_mean x Wvt0)*wPi0[100:]
    score_pass(sm.I, wsW + 0 * (size_t)FRAGS, wsW + 1 * (size_t)FRAGS, sm.tf_mean,
               wPi0, wPi0 + NK, bPi0, NR, sm.scores, sm.part2, sm.scr, tid);
    __syncthreads();

    if (tid < 64) {   // softmax over R
        float c0 = 0.f;
#pragma unroll
        for (int w = 0; w < 8; ++w) c0 += sm.scr[w];
        const float v = (tid < NR) ? sm.scores[tid] + sm.part2[tid] + c0 : -3.0e38f;
        float mx = v;
#pragma unroll
        for (int off = 32; off; off >>= 1) mx = fmaxf(mx, __shfl_xor(mx, off));
        const float e = (tid < NR) ? __expf(v - mx) : 0.f;
        float su = e;
#pragma unroll
        for (int off = 32; off; off >>= 1) su += __shfl_xor(su, off);
        sm.P[tid] = e / su;
    }
    __syncthreads();

    // ---- phase F: vi = sum_r P[r] * I[r,:]
    {
        float ax = 0.f, ay = 0.f;
        const int r0 = half ? 25 : 0, r1 = half ? NR : 25;
        for (int r = r0; r < r1; ++r) {
            const float p = sm.P[r];
            const unsigned u = *reinterpret_cast<const unsigned*>(
                &sm.I[r * 512 + (((d0 >> 3) ^ (r & 7)) << 3) + (d0 & 7)]);
            ax += p * bf16_f32((unsigned short)(u & 0xffffu));
            ay += p * bf16_f32((unsigned short)(u >> 16));
        }
        if (half) { sm.red[d0] = ax; sm.red[d0 + 1] = ay; }
        __syncthreads();
        if (!half) {
            sm.vi[d0]     = ax + sm.red[d0];
            sm.vi[d0 + 1] = ay + sm.red[d0 + 1];
        }
    }
    __syncthreads();

    // ---- pass 1: scores_t = tanh(vi x Wvi1)*wPi1[:100] + tanh(T x Wvt1)*wPi1[100:]
    score_pass(sm.T, wsW + 3 * (size_t)FRAGS, wsW + 2 * (size_t)FRAGS, sm.vi,
               wPi1 + NK, wPi1, bPi1, NS, sm.scores, sm.part2, sm.scr, tid);
    __syncthreads();

    if (tid < 64) {   // softmax over S
        float c0 = 0.f;
#pragma unroll
        for (int w = 0; w < 8; ++w) c0 += sm.scr[w];
        const float v = (tid < NS) ? sm.scores[tid] + sm.part2[tid] + c0 : -3.0e38f;
        float mx = v;
#pragma unroll
        for (int off = 32; off; off >>= 1) mx = fmaxf(mx, __shfl_xor(mx, off));
        const float e = (tid < NS) ? __expf(v - mx) : 0.f;
        float su = e;
#pragma unroll
        for (int off = 32; off; off >>= 1) su += __shfl_xor(su, off);
        sm.P[tid] = e / su;
    }
    __syncthreads();

    // ---- phase J: out = vi + sum_s P[s] * T[s,:]
    {
        float ax = 0.f, ay = 0.f;
        const int r0 = half * 25;
        for (int r = r0; r < r0 + 25; ++r) {
            const float p = sm.P[r];
            const unsigned u = *reinterpret_cast<const unsigned*>(
                &sm.T[r * 512 + (((d0 >> 3) ^ (r & 7)) << 3) + (d0 & 7)]);
            ax += p * bf16_f32((unsigned short)(u & 0xffffu));
            ay += p * bf16_f32((unsigned short)(u >> 16));
        }
        if (half) { sm.red[d0] = ax; sm.red[d0 + 1] = ay; }
        __syncthreads();
        if (!half) {
            float2 o;
            o.x = sm.vi[d0]     + ax + sm.red[d0];
            o.y = sm.vi[d0 + 1] + ay + sm.red[d0 + 1];
            *reinterpret_cast<float2*>(out + (size_t)b * ND + d0) = o;
        }
    }
}

extern "C" void kernel_launch(void* const* d_in, const int* in_sizes, int n_in,
                              void* d_out, int out_size, void* d_ws, size_t ws_size,
                              hipStream_t stream) {
    const float* ifeat = (const float*)d_in[0];
    const float* tfeat = (const float*)d_in[1];
    const float* wVi0  = (const float*)d_in[2];
    const float* wVt0  = (const float*)d_in[3];
    const float* wPi0  = (const float*)d_in[4];
    const float* bPi0  = (const float*)d_in[5];
    const float* wVi1  = (const float*)d_in[6];
    const float* wVt1  = (const float*)d_in[7];
    const float* wPi1  = (const float*)d_in[8];
    const float* bPi1  = (const float*)d_in[9];
    float* outp = (float*)d_out;
    unsigned short* wsW = (unsigned short*)d_ws;   // needs 4*114688 = 458752 B

    hipLaunchKernelGGL(preswz_kernel, dim3(NT * KSTEPS, 4), dim3(64), 0, stream,
                       wVi0, wVt0, wVi1, wVt1, wsW);
    hipLaunchKernelGGL(coattn_main, dim3(NB), dim3(512), 0, stream,
                       ifeat, tfeat, wPi0, bPi0, wPi1, bPi1, wsW, outp);
}

// Round 3
// 397.940 us; speedup vs baseline: 7.6444x; 1.6298x over previous
//
#include <hip/hip_runtime.h>
#include <math.h>

#define NB 4096
#define NR 49
#define NS 50
#define ND 512
#define NK 100
#define NT 7           // N-tiles of 16 cols (112 >= 100)
#define KSTEPS 16      // 512 / 32
#define FRAGS (NT * KSTEPS * 64 * 8)   // 57344 ushorts (114688 B) per weight matrix

typedef __attribute__((ext_vector_type(8))) short short8;
typedef __attribute__((ext_vector_type(4))) float f32x4;

__device__ __forceinline__ unsigned short f32_bf16(float f) {
    union { float f; unsigned u; } x; x.f = f;
    return (unsigned short)((x.u + 0x7fffu + ((x.u >> 16) & 1u)) >> 16);  // RNE
}
__device__ __forceinline__ float bf16_f32(unsigned short h) {
    union { unsigned u; float f; } x; x.u = ((unsigned)h) << 16;
    return x.f;
}
__device__ __forceinline__ unsigned cvt_pk_bf16(float lo, float hi) {
    unsigned r;
    asm("v_cvt_pk_bf16_f32 %0, %1, %2" : "=v"(r) : "v"(lo), "v"(hi));
    return r;  // low 16 = bf16(lo), high 16 = bf16(hi)
}
__device__ __forceinline__ float fast_tanh(float x) {
    const float ax = fabsf(x);
    const float e = __expf(2.f * ax);            // inf for large ax -> r = 1
    const float r = 1.f - 2.f / (e + 1.f);
    return copysignf(r, x);
}

// ---------------------------------------------------------------------------
// Pre-pass: weights [512][100] f32 -> bf16 MFMA B-fragments.
// frag(t, ks): lane l holds W[k = ks*32 + (l>>4)*8 + j][col = t*16 + (l&15)].
// ---------------------------------------------------------------------------
__global__ void preswz_kernel(const float* __restrict__ w0, const float* __restrict__ w1,
                              const float* __restrict__ w2, const float* __restrict__ w3,
                              unsigned short* __restrict__ ws)
{
    const int l  = threadIdx.x;          // 64
    const int ks = blockIdx.x & 15;
    const int t  = blockIdx.x >> 4;      // 0..6
    const int m  = blockIdx.y;           // 0..3
    const float* W = (m == 0) ? w0 : (m == 1) ? w1 : (m == 2) ? w2 : w3;
    const int col = t * 16 + (l & 15);
    const int k0  = ks * 32 + (l >> 4) * 8;
    unsigned short* o = ws + (size_t)m * FRAGS + ((size_t)(t * 16 + ks) * 64 + l) * 8;
#pragma unroll
    for (int j = 0; j < 8; ++j) {
        float v = (col < NK) ? W[(size_t)(k0 + j) * NK + col] : 0.f;
        o[j] = f32_bf16(v);
    }
}

// ---------------------------------------------------------------------------
// Main kernel: one block per batch, 512 threads (8 waves), 2 blocks/CU.
// ---------------------------------------------------------------------------
struct SM {
    short buf[NS * ND];             // 51200 B: bf16 feature tile (I, then reused for T)
    unsigned short cvec[ND];        // 1 KB: conditioning vector bf16 (tf_mean, then vi)
    float scores[64];               // row partials n-half 0 (incl. bias)
    float part2[64];                // row partials n-half 1
    float P[64];
    float scr[8];                   // per-wave const-GEMV partials
};

// One score pass: rows-GEMM (A[64x512] x Wrow[512x112]) + const-GEMV.
// Wave (m = wid&3) owns rows 16m..16m+15; n-half (wid>>2) owns tiles t0..t0+tcnt-1.
// nclamp = nrows-1: LDS A-reads for rows > nclamp are clamped (masked in epilogue).
__device__ __forceinline__ void score_pass(
    const short* __restrict__ At, const unsigned short* __restrict__ wsR,
    const unsigned short* __restrict__ wsC, const unsigned short* __restrict__ cvec,
    const float* __restrict__ wPiRow, const float* __restrict__ wPiConst,
    const float* __restrict__ bvec, int nrows, int nclamp,
    float* __restrict__ outA, float* __restrict__ outB, float* __restrict__ scrw, int tid)
{
    const int lane = tid & 63, wid = tid >> 6;
    const int m = wid & 3, nh = wid >> 2;
    const int t0 = nh * 4, tcnt = nh ? 3 : 4;
    const int colg = lane & 15, g = lane >> 4;
    const int arow0 = m * 16 + colg;
    const int arow = (arow0 < nclamp) ? arow0 : nclamp;   // clamp padded rows
    const int rswz = arow & 7;

    const unsigned short* wbase[4];
#pragma unroll
    for (int q = 0; q < 4; ++q)
        wbase[q] = wsR + (size_t)(t0 + q) * (KSTEPS * 512) + lane * 8;

    const f32x4 zero4 = {0.f, 0.f, 0.f, 0.f};
    f32x4 acc[4] = {zero4, zero4, zero4, zero4};

    short8 wf[4];
#pragma unroll
    for (int q = 0; q < 4; ++q)
        if (q < tcnt) wf[q] = *reinterpret_cast<const short8*>(wbase[q]);

    for (int ks = 0; ks < KSTEPS; ++ks) {
        const short8 a = *reinterpret_cast<const short8*>(
            &At[arow * 512 + (((ks * 4 + g) ^ rswz) << 3)]);
        short8 wn[4];
        if (ks + 1 < KSTEPS) {
#pragma unroll
            for (int q = 0; q < 4; ++q)
                if (q < tcnt) wn[q] = *reinterpret_cast<const short8*>(wbase[q] + (ks + 1) * 512);
        } else {
#pragma unroll
            for (int q = 0; q < 4; ++q) wn[q] = wf[q];
        }
#pragma unroll
        for (int q = 0; q < 4; ++q)
            if (q < tcnt) acc[q] = __builtin_amdgcn_mfma_f32_16x16x32_bf16(a, wf[q], acc[q], 0, 0, 0);
#pragma unroll
        for (int q = 0; q < 4; ++q) wf[q] = wn[q];
    }

    // rows epilogue: s[row] = sum_cols tanh(D) * wPiRow; shfl-reduce 16 col-lanes
    float s[4] = {0.f, 0.f, 0.f, 0.f};
#pragma unroll
    for (int q = 0; q < 4; ++q)
        if (q < tcnt) {
            const int col = (t0 + q) * 16 + colg;
            const float w = (col < NK) ? wPiRow[col] : 0.f;
#pragma unroll
            for (int i = 0; i < 4; ++i) s[i] += fast_tanh(acc[q][i]) * w;
        }
#pragma unroll
    for (int off = 1; off < 16; off <<= 1) {
#pragma unroll
        for (int i = 0; i < 4; ++i) s[i] += __shfl_xor(s[i], off);
    }
    if (colg == 0) {
        float* o = nh ? outB : outA;
        const int rbase = m * 16 + g * 4;
#pragma unroll
        for (int i = 0; i < 4; ++i) {
            const int r = rbase + i;
            if (r < nrows) o[r] = s[i] + (nh ? 0.f : bvec[r]);
        }
    }

    // const GEMV: wave wid (<7) computes row-0-only MFMA tile of cvec x Wconst
    f32x4 accC = zero4;
    if (wid < NT) {
        const unsigned short* wc = wsC + (size_t)wid * (KSTEPS * 512) + lane * 8;
        for (int ks = 0; ks < KSTEPS; ++ks) {
            const short8 cv = *reinterpret_cast<const short8*>(&cvec[ks * 32 + g * 8]);
            short8 a = {0, 0, 0, 0, 0, 0, 0, 0};
            if (colg == 0) a = cv;
            const short8 w = *reinterpret_cast<const short8*>(wc + ks * 512);
            accC = __builtin_amdgcn_mfma_f32_16x16x32_bf16(a, w, accC, 0, 0, 0);
        }
    }
    float cpv = 0.f;
    if (wid < NT && lane < 16) {
        const int col = wid * 16 + colg;
        if (col < NK) cpv = fast_tanh(accC[0]) * wPiConst[col];
    }
#pragma unroll
    for (int off = 1; off < 16; off <<= 1) cpv += __shfl_xor(cpv, off);
    if (lane == 0) scrw[wid] = cpv;
}

__global__ __launch_bounds__(512, 4) void coattn_main(
    const float* __restrict__ ifeat, const float* __restrict__ tfeat,
    const float* __restrict__ wPi0, const float* __restrict__ bPi0,
    const float* __restrict__ wPi1, const float* __restrict__ bPi1,
    const unsigned short* __restrict__ wsW, float* __restrict__ out)
{
    __shared__ SM sm;
    const int b = blockIdx.x, tid = threadIdx.x;
    const float* ig = ifeat + (size_t)b * NR * ND;
    const float* tg = tfeat + (size_t)b * NS * ND;

    // ---- stage I -> LDS (bf16, 16B-chunk XOR swizzle); T -> registers; tf_mean
    for (int ci = tid; ci < NR * 64; ci += 512) {
        const int row = ci >> 6, c = ci & 63;
        const float* p = ig + (row << 9) + (c << 3);
        const float4 a  = *reinterpret_cast<const float4*>(p);
        const float4 b4 = *reinterpret_cast<const float4*>(p + 4);
        uint4 v;
        v.x = cvt_pk_bf16(a.x, a.y);   v.y = cvt_pk_bf16(a.z, a.w);
        v.z = cvt_pk_bf16(b4.x, b4.y); v.w = cvt_pk_bf16(b4.z, b4.w);
        *reinterpret_cast<uint4*>(&sm.buf[(row << 9) + ((c ^ (row & 7)) << 3)]) = v;
    }
    unsigned treg[25];      // T[0..49][tid] as packed bf16 pairs (rows 2j, 2j+1)
    {
        float msum = 0.f;
        const float* tp = tg + tid;
#pragma unroll
        for (int j = 0; j < 25; ++j) {
            const float v0 = tp[(2 * j) * ND];
            const float v1 = tp[(2 * j + 1) * ND];
            msum += v0 + v1;
            treg[j] = cvt_pk_bf16(v0, v1);
        }
        sm.cvec[tid] = f32_bf16(msum * (1.f / NS));
    }
    __syncthreads();

    // ---- pass 0: scores_i
    score_pass(sm.buf, wsW + 0 * (size_t)FRAGS, wsW + 1 * (size_t)FRAGS, sm.cvec,
               wPi0, wPi0 + NK, bPi0, NR, NR - 1, sm.scores, sm.part2, sm.scr, tid);
    __syncthreads();

    if (tid < 64) {   // softmax over R
        float c0 = 0.f;
#pragma unroll
        for (int w = 0; w < 8; ++w) c0 += sm.scr[w];
        const float v = (tid < NR) ? sm.scores[tid] + sm.part2[tid] + c0 : -3.0e38f;
        float mx = v;
#pragma unroll
        for (int off = 32; off; off >>= 1) mx = fmaxf(mx, __shfl_xor(mx, off));
        const float e = (tid < NR) ? __expf(v - mx) : 0.f;
        float su = e;
#pragma unroll
        for (int off = 32; off; off >>= 1) su += __shfl_xor(su, off);
        sm.P[tid] = e / su;
    }
    __syncthreads();

    // ---- phase F: vi[tid] = sum_r P[r] * I[r, tid]  (thread-per-column)
    float vi = 0.f;
    {
        const int ch = tid >> 3, lo = tid & 7;
        for (int r = 0; r < NR; ++r) {
            const unsigned short u = (unsigned short)sm.buf[r * 512 + ((ch ^ (r & 7)) << 3) + lo];
            vi += sm.P[r] * bf16_f32(u);
        }
    }
    __syncthreads();   // I-LDS reads complete before overwrite

    // ---- dump T regs -> LDS (same swizzle); cvec <- bf16(vi)
    {
        const int ch = tid >> 3, lo = tid & 7;
#pragma unroll
        for (int j = 0; j < 25; ++j) {
            const unsigned u = treg[j];
            const int r0 = 2 * j, r1 = 2 * j + 1;
            sm.buf[r0 * 512 + ((ch ^ (r0 & 7)) << 3) + lo] = (short)(u & 0xffffu);
            sm.buf[r1 * 512 + ((ch ^ (r1 & 7)) << 3) + lo] = (short)(u >> 16);
        }
        sm.cvec[tid] = f32_bf16(vi);
    }
    __syncthreads();

    // ---- pass 1: scores_t
    score_pass(sm.buf, wsW + 3 * (size_t)FRAGS, wsW + 2 * (size_t)FRAGS, sm.cvec,
               wPi1 + NK, wPi1, bPi1, NS, NS - 1, sm.scores, sm.part2, sm.scr, tid);
    __syncthreads();

    if (tid < 64) {   // softmax over S
        float c0 = 0.f;
#pragma unroll
        for (int w = 0; w < 8; ++w) c0 += sm.scr[w];
        const float v = (tid < NS) ? sm.scores[tid] + sm.part2[tid] + c0 : -3.0e38f;
        float mx = v;
#pragma unroll
        for (int off = 32; off; off >>= 1) mx = fmaxf(mx, __shfl_xor(mx, off));
        const float e = (tid < NS) ? __expf(v - mx) : 0.f;
        float su = e;
#pragma unroll
        for (int off = 32; off; off >>= 1) su += __shfl_xor(su, off);
        sm.P[tid] = e / su;
    }
    __syncthreads();

    // ---- phase J: out[tid] = vi + sum_s P[s] * T[s, tid]   (pure registers)
    {
        float o = vi;
#pragma unroll
        for (int j = 0; j < 25; ++j) {
            const unsigned u = treg[j];
            o += sm.P[2 * j]     * bf16_f32((unsigned short)(u & 0xffffu));
            o += sm.P[2 * j + 1] * bf16_f32((unsigned short)(u >> 16));
        }
        out[(size_t)b * ND + tid] = o;
    }
}

extern "C" void kernel_launch(void* const* d_in, const int* in_sizes, int n_in,
                              void* d_out, int out_size, void* d_ws, size_t ws_size,
                              hipStream_t stream) {
    const float* ifeat = (const float*)d_in[0];
    const float* tfeat = (const float*)d_in[1];
    const float* wVi0  = (const float*)d_in[2];
    const float* wVt0  = (const float*)d_in[3];
    const float* wPi0  = (const float*)d_in[4];
    const float* bPi0  = (const float*)d_in[5];
    const float* wVi1  = (const float*)d_in[6];
    const float* wVt1  = (const float*)d_in[7];
    const float* wPi1  = (const float*)d_in[8];
    const float* bPi1  = (const float*)d_in[9];
    float* outp = (float*)d_out;
    unsigned short* wsW = (unsigned short*)d_ws;   // 4*114688 = 458752 B

    hipLaunchKernelGGL(preswz_kernel, dim3(NT * KSTEPS, 4), dim3(64), 0, stream,
                       wVi0, wVt0, wVi1, wVt1, wsW);
    hipLaunchKernelGGL(coattn_main, dim3(NB), dim3(512), 0, stream,
                       ifeat, tfeat, wPi0, bPi0, wPi1, bPi1, wsW, outp);
}